// Round 3
// baseline (404.981 us; speedup 1.0000x reference)
//
#include <hip/hip_runtime.h>
#include <hip/hip_fp16.h>

#define B_  8
#define D_  512
#define H_  512
#define L_  8192
#define O2_ 1024   // 2*H

typedef __attribute__((ext_vector_type(8))) short   bf16x8;
typedef __attribute__((ext_vector_type(4))) float   floatx4;
typedef __attribute__((ext_vector_type(8))) unsigned short ushort8_t;
typedef __attribute__((ext_vector_type(4))) unsigned short ushort4_t;

__device__ __forceinline__ unsigned short f2bf(float f) {
    union { float f; unsigned u; } x; x.f = f;
    unsigned u = x.u;
    u += 0x7FFFu + ((u >> 16) & 1u);   // round-to-nearest-even
    return (unsigned short)(u >> 16);
}

// async global->LDS, 16B per lane; LDS dest = wave-uniform base + lane*16
__device__ __forceinline__ void async_load16(const void* g, void* l) {
    __builtin_amdgcn_global_load_lds(
        (const __attribute__((address_space(1))) unsigned int*)g,
        (__attribute__((address_space(3))) unsigned int*)l,
        16, 0, 0);
}

// ---------------- K0: reorder W rows (pair-interleave) + convert to bf16 ----
__global__ __launch_bounds__(256) void prep_w(const float* __restrict__ W,
                                              unsigned short* __restrict__ Wr) {
    int idx  = blockIdx.x * 256 + threadIdx.x;
    int flat = idx * 4;
    int o = flat >> 9;        // /512
    int d = flat & 511;
    int src_o = (o & 1) ? (H_ + (o >> 1)) : (o >> 1);
    float4 wv = *(const float4*)(W + (size_t)src_o * D_ + d);
    ushort4_t r;
    r.x = f2bf(wv.x); r.y = f2bf(wv.y); r.z = f2bf(wv.z); r.w = f2bf(wv.w);
    *(ushort4_t*)(Wr + (size_t)o * D_ + d) = r;
}

// ---------------- K1: hg = Wr @ x  (transpose FUSED into B-staging) ---------
// Proven 128x128 / 4-wave / 2-barrier structure (97us version).
// A: DMA from Wr with source-permuted XOR swizzle (unchanged).
// B: reg-staged transpose of x [D][L] fp32 -> Bs [l][d] bf16 with the SAME
//    swizzle key (l&7) the fragment reads use: thread owns an 8d x 4l patch,
//    loads 8 coalesced float4 (2x512B per wave-instr), transposes in regs,
//    writes 4x ds_write_b128 to phys chunk g^(l&7).
// T14 split: next tile's x-loads issue after the leading barrier (fly under
// MFMA); trailing barrier is lgkm-only so they survive it; compiler inserts
// the counted vmcnt before xr's use next iteration.
__global__ __launch_bounds__(256) void gemm_fused(const float* __restrict__ x,
                                                  const unsigned short* __restrict__ Wr,
                                                  __half* __restrict__ hg) {
    __shared__ __align__(16) unsigned short As[128][64];   // 16 KB
    __shared__ __align__(16) unsigned short Bs[128][64];   // 16 KB

    const int b  = blockIdx.z;
    const int o0 = blockIdx.x * 128;     // o fastest: 8 blocks share an x l-panel
    const int l0 = blockIdx.y * 128;
    const int tid  = threadIdx.x;
    const int lane = tid & 63;
    const int w    = tid >> 6;
    const int wm   = (w >> 1) * 64;
    const int wn   = (w & 1) * 64;
    const int lm   = lane & 15;
    const int quad = lane >> 4;

    // A staging: lane i -> row +(i>>3), phys chunk i&7 sources logical (i&7)^(i>>3)
    const int sj  = lane >> 3;
    const int scg = (lane & 7) ^ sj;
    const unsigned short* Ag = Wr + (size_t)(o0 + w * 32 + sj) * D_ + scg * 8;

    // B staging: thread owns rows d = g*8..g*8+7, cols l = c*4..c*4+3
    const int c = tid & 31;
    const int g = tid >> 5;
    const float* xg = x + ((size_t)b * D_ + g * 8) * L_ + l0 + c * 4;

    float4 xr[8];
    #pragma unroll
    for (int rr = 0; rr < 8; ++rr)
        xr[rr] = *(const float4*)(xg + (size_t)rr * L_);

    floatx4 acc[4][4];
    #pragma unroll
    for (int mi = 0; mi < 4; ++mi)
        #pragma unroll
        for (int ni = 0; ni < 4; ++ni)
            acc[mi][ni] = (floatx4){0.f, 0.f, 0.f, 0.f};

    for (int kk = 0; kk < 8; ++kk) {
        const int k0 = kk * 64;
        // A: DMA issue (4 x 1KB per wave)
        #pragma unroll
        for (int p = 0; p < 4; ++p)
            async_load16(Ag + (size_t)(p * 8) * D_ + k0, &As[w * 32 + p * 8][0]);

        // B: register transpose + bf16 cvt + swizzled ds_write_b128
        // (first use of xr -> compiler inserts counted vmcnt for the prefetch)
        #pragma unroll
        for (int j = 0; j < 4; ++j) {
            ushort8_t o8;
            #pragma unroll
            for (int rr = 0; rr < 8; ++rr)
                o8[rr] = f2bf(((const float*)&xr[rr])[j]);
            const int l    = c * 4 + j;
            const int phys = g ^ (l & 7);
            *(ushort8_t*)((char*)&Bs[l][0] + phys * 16) = o8;
        }

        __syncthreads();   // drains A-DMA (vmcnt) + B ds_writes (lgkm)

        // prefetch next x-tile: flies under the MFMA phase
        if (kk < 7) {
            #pragma unroll
            for (int rr = 0; rr < 8; ++rr)
                xr[rr] = *(const float4*)(xg + (size_t)((kk + 1) * 64 + rr) * L_);
        }

        #pragma unroll
        for (int ks = 0; ks < 2; ++ks) {
            const int lc = ks * 4 + quad;      // logical 16B chunk (=koff/8)
            bf16x8 af[4], bfv[4];
            #pragma unroll
            for (int mi = 0; mi < 4; ++mi) {
                const int r = wm + mi * 16 + lm;
                af[mi] = *(const bf16x8*)&As[r][(lc ^ (r & 7)) * 8];
            }
            #pragma unroll
            for (int ni = 0; ni < 4; ++ni) {
                const int r = wn + ni * 16 + lm;
                bfv[ni] = *(const bf16x8*)&Bs[r][(lc ^ (r & 7)) * 8];
            }
            #pragma unroll
            for (int mi = 0; mi < 4; ++mi)
                #pragma unroll
                for (int ni = 0; ni < 4; ++ni)
                    acc[mi][ni] = __builtin_amdgcn_mfma_f32_16x16x32_bf16(
                        af[mi], bfv[ni], acc[mi][ni], 0, 0, 0);
        }

        // trailing sync: lgkm-only (fragment reads already consumed) so the
        // x-prefetch stays in flight across the barrier (T14 wait-late)
        asm volatile("s_waitcnt lgkmcnt(0)" ::: "memory");
        __builtin_amdgcn_s_barrier();
        asm volatile("" ::: "memory");
    }

    // epilogue: D[row=quad*4+r][col=lm] per 16x16 tile (proven mapping)
    __half* hp = hg + ((size_t)b * O2_ + o0 + wm + quad * 4) * L_ + l0 + wn + lm;
    for (int mi = 0; mi < 4; ++mi)
        for (int ni = 0; ni < 4; ++ni)
            for (int r = 0; r < 4; ++r)
                hp[(size_t)(mi * 16 + r) * L_ + ni * 16] = __float2half(acc[mi][ni][r]);
}

// ---------------- K2: per-(b,k) chunked scan — shfl wave scan, 3 barriers ---
__global__ __launch_bounds__(256) void scan_seq(const __half* __restrict__ hg,
                                                const float* __restrict__ bias,
                                                float* __restrict__ out) {
    __shared__ __align__(16) unsigned int sBuf[256 * 40];
    __shared__ float wA[4];
    __shared__ float wB[4];
    unsigned int* sH = sBuf;
    unsigned int* sG = sBuf + 256 * 20;

    const int bid = blockIdx.x;
    const int b = bid >> 9;
    const int k = bid & 511;
    const int t = threadIdx.x;
    const int lane = t & 63;
    const int wid  = t >> 6;

    const uint4* hq = (const uint4*)(hg + ((size_t)b * O2_ + 2 * k) * L_);
    const uint4* gq = hq + (L_ / 8);   // next row (gate)

    #pragma unroll
    for (int j = 0; j < 4; ++j) {
        int idx = t + 256 * j;               // uint4 index 0..1023
        uint4 hv = hq[idx];
        uint4 gv = gq[idx];
        int cc = idx >> 2, ss = idx & 3;     // chunk 16 uints, pad to 20
        *(uint4*)&sH[cc * 20 + ss * 4] = hv;
        *(uint4*)&sG[cc * 20 + ss * 4] = gv;
    }
    const float bh = bias[k];
    const float bg = bias[H_ + k];
    __syncthreads();                                           // barrier 1

    float c[32], v[32];
    float A = 1.f, Bv = 0.f;
    #pragma unroll
    for (int j4 = 0; j4 < 4; ++j4) {
        uint4 hv = *(const uint4*)&sH[t * 20 + j4 * 4];
        uint4 gv = *(const uint4*)&sG[t * 20 + j4 * 4];
        unsigned hu[4] = {hv.x, hv.y, hv.z, hv.w};
        unsigned gu[4] = {gv.x, gv.y, gv.z, gv.w};
        #pragma unroll
        for (int q = 0; q < 4; ++q) {
            __half2 h2 = *(const __half2*)&hu[q];
            __half2 g2 = *(const __half2*)&gu[q];
            #pragma unroll
            for (int e = 0; e < 2; ++e) {
                const int i = j4 * 8 + q * 2 + e;
                float hf = (e ? __high2float(h2) : __low2float(h2)) + bh;
                float gf = (e ? __high2float(g2) : __low2float(g2)) + bg;
                float ex  = __expf(gf);
                float inv = 1.f / (1.f + ex);
                float ci  = inv;        // sigmoid(-gate)
                float zi  = ex * inv;   // sigmoid(gate)
                float gv2 = (hf >= 0.f) ? (1.f + hf) : __expf(hf);
                float vi  = zi * gv2;
                c[i] = ci; v[i] = vi;
                Bv = ci * Bv + vi;
                A *= ci;
            }
        }
    }

    // wave-level inclusive scan of (A,B) composition, no barriers
    #pragma unroll
    for (int off = 1; off < 64; off <<= 1) {
        float pA = __shfl_up(A, off);
        float pB = __shfl_up(Bv, off);
        if (lane >= off) { Bv = Bv + A * pB; A = A * pA; }
    }

    if (lane == 63) { wA[wid] = A; wB[wid] = Bv; }
    __syncthreads();                                           // barrier 2

    // carry from preceding waves (composed in order)
    float cB = 0.f;
    for (int p = 0; p < wid; ++p) cB = wB[p] + wA[p] * cB;

    // exclusive lane prefix within wave
    float eA = __shfl_up(A, 1);
    float eB = __shfl_up(Bv, 1);
    if (lane == 0) { eA = 1.f; eB = 0.f; }
    float hr = eB + eA * cB;   // H entering this thread's chunk (H0 = 0)

    // outputs into LDS (chunk stride 36 floats), then coalesced store.
    float* sO = (float*)sBuf;
    #pragma unroll
    for (int i = 0; i < 32; i += 4) {
        float4 o4;
        o4.x = hr = c[i + 0] * hr + v[i + 0];
        o4.y = hr = c[i + 1] * hr + v[i + 1];
        o4.z = hr = c[i + 2] * hr + v[i + 2];
        o4.w = hr = c[i + 3] * hr + v[i + 3];
        *(float4*)&sO[t * 36 + i] = o4;
    }
    __syncthreads();                                           // barrier 3

    float4* op4 = (float4*)(out + ((size_t)b * H_ + k) * L_);
    #pragma unroll
    for (int j = 0; j < 8; ++j) {
        int idx = t + 256 * j;               // float4 index 0..2047
        int cc = idx >> 3, ss = idx & 7;     // chunk 32 floats, pad to 36
        op4[idx] = *(const float4*)&sO[cc * 36 + ss * 4];
    }
}

// ---------------- fallback: fully fused naive (if ws too small) -------------
__global__ __launch_bounds__(256) void fused_naive(const float* __restrict__ x,
                                                   const float* __restrict__ W,
                                                   const float* __restrict__ bias,
                                                   float* __restrict__ out) {
    __shared__ float Wh[512];
    __shared__ float Wg[512];
    __shared__ float sA[256];
    __shared__ float sB[256];
    const int bid = blockIdx.x;
    const int b = bid >> 9;
    const int k = bid & 511;
    const int t = threadIdx.x;

    for (int i = t; i < 512; i += 256) {
        Wh[i] = W[(size_t)k * D_ + i];
        Wg[i] = W[(size_t)(H_ + k) * D_ + i];
    }
    const float bh = bias[k];
    const float bg = bias[H_ + k];
    __syncthreads();

    float Hc = 0.f;
    const float* xb = x + (size_t)b * D_ * L_;
    for (int ch = 0; ch < 32; ++ch) {
        const int l = ch * 256 + t;
        float ah = bh, ag = bg;
        for (int d = 0; d < 512; ++d) {
            float xv = xb[(size_t)d * L_ + l];
            ah += Wh[d] * xv;
            ag += Wg[d] * xv;
        }
        float e   = __expf(ag);
        float inv = 1.f / (1.f + e);
        float ci  = inv;
        float zi  = e * inv;
        float gv  = (ah >= 0.f) ? (1.f + ah) : __expf(ah);
        float vi  = zi * gv;

        float A = ci, Bv = vi;
        sA[t] = A; sB[t] = Bv;
        __syncthreads();
        for (int off = 1; off < 256; off <<= 1) {
            float pA = 1.f, pB = 0.f;
            if (t >= off) { pA = sA[t - off]; pB = sB[t - off]; }
            __syncthreads();
            Bv = Bv + A * pB;
            A  = A * pA;
            sA[t] = A; sB[t] = Bv;
            __syncthreads();
        }
        out[((size_t)b * H_ + k) * L_ + l] = A * Hc + Bv;
        float An = sA[255], Bn = sB[255];
        Hc = An * Hc + Bn;
        __syncthreads();
    }
}

extern "C" void kernel_launch(void* const* d_in, const int* in_sizes, int n_in,
                              void* d_out, int out_size, void* d_ws, size_t ws_size,
                              hipStream_t stream) {
    const float* x    = (const float*)d_in[0];
    const float* W    = (const float*)d_in[1];
    const float* bias = (const float*)d_in[2];
    float* out = (float*)d_out;

    const size_t Wr_bytes = (size_t)O2_ * D_ * 2;            //   1,048,576
    const size_t hg_bytes = (size_t)B_ * O2_ * L_ * 2;       // 134,217,728
    const size_t need = Wr_bytes + hg_bytes;                 // ~135 MB

    if (ws_size >= need) {
        char* ws = (char*)d_ws;
        unsigned short* Wr = (unsigned short*)ws;
        __half*         hg = (__half*)(ws + Wr_bytes);

        prep_w<<<512, 256, 0, stream>>>(W, Wr);
        gemm_fused<<<dim3(O2_ / 128, L_ / 128, B_), 256, 0, stream>>>(x, Wr, hg);
        scan_seq<<<B_ * H_, 256, 0, stream>>>(hg, bias, out);
    } else {
        fused_naive<<<B_ * H_, 256, 0, stream>>>(x, W, bias, out);
    }
}

// Round 4
// 362.105 us; speedup vs baseline: 1.1184x; 1.1184x over previous
//
#include <hip/hip_runtime.h>
#include <hip/hip_fp16.h>

#define B_  8
#define D_  512
#define H_  512
#define L_  8192
#define O2_ 1024   // 2*H

typedef __attribute__((ext_vector_type(8))) short   bf16x8;
typedef __attribute__((ext_vector_type(4))) float   floatx4;
typedef __attribute__((ext_vector_type(8))) unsigned short ushort8_t;
typedef __attribute__((ext_vector_type(4))) unsigned short ushort4_t;

__device__ __forceinline__ unsigned short f2bf(float f) {
    union { float f; unsigned u; } x; x.f = f;
    unsigned u = x.u;
    u += 0x7FFFu + ((u >> 16) & 1u);   // round-to-nearest-even
    return (unsigned short)(u >> 16);
}

// async global->LDS, 16B per lane; LDS dest = wave-uniform base + lane*16
__device__ __forceinline__ void async_load16(const void* g, void* l) {
    __builtin_amdgcn_global_load_lds(
        (const __attribute__((address_space(1))) unsigned int*)g,
        (__attribute__((address_space(3))) unsigned int*)l,
        16, 0, 0);
}

// ---------------- K0: reorder W rows (pair-interleave) + convert to bf16 ----
__global__ __launch_bounds__(256) void prep_w(const float* __restrict__ W,
                                              unsigned short* __restrict__ Wr) {
    int idx  = blockIdx.x * 256 + threadIdx.x;
    int flat = idx * 4;
    int o = flat >> 9;        // /512
    int d = flat & 511;
    int src_o = (o & 1) ? (H_ + (o >> 1)) : (o >> 1);
    float4 wv = *(const float4*)(W + (size_t)src_o * D_ + d);
    ushort4_t r;
    r.x = f2bf(wv.x); r.y = f2bf(wv.y); r.z = f2bf(wv.z); r.w = f2bf(wv.w);
    *(ushort4_t*)(Wr + (size_t)o * D_ + d) = r;
}

// ---------------- K1: hg = Wr @ x  (transpose FUSED into B-staging) ---------
// 128x128 / 4-wave / 2-barrier structure.
// A: DMA from Wr, perm_A(r) = r&7 (write via source perm, read lc^(r&7)) —
//    conflict-free both sides (unchanged from the proven 97us kernel).
// B: reg-staged transpose of x [D][L] fp32 -> Bs bf16 with perm_B(l) =
//    ((l>>2)&7)^(l&3), SAME function on write and read:
//    - write: thread (c,g) writes row l=4c+j, phys = g^(c&7)^j -> per 8-lane
//      phase 8 distinct 16B columns = conflict-FREE (was 16-way in r3).
//    - read: lanes lm=0..7 -> perm covers 4 values x2 = 2-way (free, m136).
// Grid (l,o,b): the 8 o-sibling blocks sharing an x l-panel have flat IDs
// spaced 64 (= 0 mod 8 XCDs) -> same XCD -> panel fetched once per L2.
__global__ __launch_bounds__(256) void gemm_fused(const float* __restrict__ x,
                                                  const unsigned short* __restrict__ Wr,
                                                  __half* __restrict__ hg) {
    __shared__ __align__(16) unsigned short As[128][64];   // 16 KB
    __shared__ __align__(16) unsigned short Bs[128][64];   // 16 KB

    const int b  = blockIdx.z;
    const int l0 = blockIdx.x * 128;     // l fastest -> o-siblings same XCD
    const int o0 = blockIdx.y * 128;
    const int tid  = threadIdx.x;
    const int lane = tid & 63;
    const int w    = tid >> 6;
    const int wm   = (w >> 1) * 64;
    const int wn   = (w & 1) * 64;
    const int lm   = lane & 15;
    const int quad = lane >> 4;

    // A staging: lane i -> row +(i>>3), phys chunk i&7 sources logical (i&7)^(i>>3)
    const int sj  = lane >> 3;
    const int scg = (lane & 7) ^ sj;
    const unsigned short* Ag = Wr + (size_t)(o0 + w * 32 + sj) * D_ + scg * 8;

    // B staging: thread owns rows d = g*8..g*8+7, cols l = c*4..c*4+3
    const int c = tid & 31;
    const int g = tid >> 5;
    const float* xg = x + ((size_t)b * D_ + g * 8) * L_ + l0 + c * 4;

    float4 xr[8];
    #pragma unroll
    for (int rr = 0; rr < 8; ++rr)
        xr[rr] = *(const float4*)(xg + (size_t)rr * L_);

    floatx4 acc[4][4];
    #pragma unroll
    for (int mi = 0; mi < 4; ++mi)
        #pragma unroll
        for (int ni = 0; ni < 4; ++ni)
            acc[mi][ni] = (floatx4){0.f, 0.f, 0.f, 0.f};

    // read-side perm_B pieces: perm_B(r) = ((ni*4 + (lm>>2)) & 7) ^ (lm & 3)
    const int pbq = lm >> 2;
    const int pbx = lm & 3;

    for (int kk = 0; kk < 8; ++kk) {
        const int k0 = kk * 64;
        // A: DMA issue (4 x 1KB per wave)
        #pragma unroll
        for (int p = 0; p < 4; ++p)
            async_load16(Ag + (size_t)(p * 8) * D_ + k0, &As[w * 32 + p * 8][0]);

        // B: register transpose + bf16 cvt + swizzled ds_write_b128
        #pragma unroll
        for (int j = 0; j < 4; ++j) {
            ushort8_t o8;
            #pragma unroll
            for (int rr = 0; rr < 8; ++rr)
                o8[rr] = f2bf(((const float*)&xr[rr])[j]);
            const int phys = g ^ (c & 7) ^ j;            // perm_B(4c+j) = (c&7)^j
            *(ushort8_t*)&Bs[c * 4 + j][phys * 8] = o8;
        }

        __syncthreads();   // drains A-DMA (vmcnt) + B ds_writes (lgkm)

        // prefetch next x-tile: flies under the MFMA phase
        if (kk < 7) {
            #pragma unroll
            for (int rr = 0; rr < 8; ++rr)
                xr[rr] = *(const float4*)(xg + (size_t)((kk + 1) * 64 + rr) * L_);
        }

        #pragma unroll
        for (int ks = 0; ks < 2; ++ks) {
            const int lc = ks * 4 + quad;      // logical 16B chunk (=koff/8)
            bf16x8 af[4], bfv[4];
            #pragma unroll
            for (int mi = 0; mi < 4; ++mi) {
                const int r = wm + mi * 16 + lm;
                af[mi] = *(const bf16x8*)&As[r][(lc ^ (r & 7)) * 8];
            }
            #pragma unroll
            for (int ni = 0; ni < 4; ++ni) {
                const int r = wn + ni * 16 + lm;
                const int permB = ((ni * 4 + pbq) & 7) ^ pbx;
                bfv[ni] = *(const bf16x8*)&Bs[r][(lc ^ permB) * 8];
            }
            #pragma unroll
            for (int mi = 0; mi < 4; ++mi)
                #pragma unroll
                for (int ni = 0; ni < 4; ++ni)
                    acc[mi][ni] = __builtin_amdgcn_mfma_f32_16x16x32_bf16(
                        af[mi], bfv[ni], acc[mi][ni], 0, 0, 0);
        }

        // trailing sync: lgkm-only so the x-prefetch stays in flight (T14)
        asm volatile("s_waitcnt lgkmcnt(0)" ::: "memory");
        __builtin_amdgcn_s_barrier();
        asm volatile("" ::: "memory");
    }

    // epilogue: D[row=quad*4+r][col=lm] per 16x16 tile (proven mapping)
    __half* hp = hg + ((size_t)b * O2_ + o0 + wm + quad * 4) * L_ + l0 + wn + lm;
    for (int mi = 0; mi < 4; ++mi)
        for (int ni = 0; ni < 4; ++ni)
            for (int r = 0; r < 4; ++r)
                hp[(size_t)(mi * 16 + r) * L_ + ni * 16] = __float2half(acc[mi][ni][r]);
}

// ---------------- K2: per-(b,k) chunked scan — shfl wave scan, 3 barriers ---
__global__ __launch_bounds__(256) void scan_seq(const __half* __restrict__ hg,
                                                const float* __restrict__ bias,
                                                float* __restrict__ out) {
    __shared__ __align__(16) unsigned int sBuf[256 * 40];
    __shared__ float wA[4];
    __shared__ float wB[4];
    unsigned int* sH = sBuf;
    unsigned int* sG = sBuf + 256 * 20;

    const int bid = blockIdx.x;
    const int b = bid >> 9;
    const int k = bid & 511;
    const int t = threadIdx.x;
    const int lane = t & 63;
    const int wid  = t >> 6;

    const uint4* hq = (const uint4*)(hg + ((size_t)b * O2_ + 2 * k) * L_);
    const uint4* gq = hq + (L_ / 8);   // next row (gate)

    #pragma unroll
    for (int j = 0; j < 4; ++j) {
        int idx = t + 256 * j;               // uint4 index 0..1023
        uint4 hv = hq[idx];
        uint4 gv = gq[idx];
        int cc = idx >> 2, ss = idx & 3;     // chunk 16 uints, pad to 20
        *(uint4*)&sH[cc * 20 + ss * 4] = hv;
        *(uint4*)&sG[cc * 20 + ss * 4] = gv;
    }
    const float bh = bias[k];
    const float bg = bias[H_ + k];
    __syncthreads();                                           // barrier 1

    float c[32], v[32];
    float A = 1.f, Bv = 0.f;
    #pragma unroll
    for (int j4 = 0; j4 < 4; ++j4) {
        uint4 hv = *(const uint4*)&sH[t * 20 + j4 * 4];
        uint4 gv = *(const uint4*)&sG[t * 20 + j4 * 4];
        unsigned hu[4] = {hv.x, hv.y, hv.z, hv.w};
        unsigned gu[4] = {gv.x, gv.y, gv.z, gv.w};
        #pragma unroll
        for (int q = 0; q < 4; ++q) {
            __half2 h2 = *(const __half2*)&hu[q];
            __half2 g2 = *(const __half2*)&gu[q];
            #pragma unroll
            for (int e = 0; e < 2; ++e) {
                const int i = j4 * 8 + q * 2 + e;
                float hf = (e ? __high2float(h2) : __low2float(h2)) + bh;
                float gf = (e ? __high2float(g2) : __low2float(g2)) + bg;
                float ex  = __expf(gf);
                float inv = 1.f / (1.f + ex);
                float ci  = inv;        // sigmoid(-gate)
                float zi  = ex * inv;   // sigmoid(gate)
                float gv2 = (hf >= 0.f) ? (1.f + hf) : __expf(hf);
                float vi  = zi * gv2;
                c[i] = ci; v[i] = vi;
                Bv = ci * Bv + vi;
                A *= ci;
            }
        }
    }

    // wave-level inclusive scan of (A,B) composition, no barriers
    #pragma unroll
    for (int off = 1; off < 64; off <<= 1) {
        float pA = __shfl_up(A, off);
        float pB = __shfl_up(Bv, off);
        if (lane >= off) { Bv = Bv + A * pB; A = A * pA; }
    }

    if (lane == 63) { wA[wid] = A; wB[wid] = Bv; }
    __syncthreads();                                           // barrier 2

    // carry from preceding waves (composed in order)
    float cB = 0.f;
    for (int p = 0; p < wid; ++p) cB = wB[p] + wA[p] * cB;

    // exclusive lane prefix within wave
    float eA = __shfl_up(A, 1);
    float eB = __shfl_up(Bv, 1);
    if (lane == 0) { eA = 1.f; eB = 0.f; }
    float hr = eB + eA * cB;   // H entering this thread's chunk (H0 = 0)

    // outputs into LDS (chunk stride 36 floats), then coalesced store.
    float* sO = (float*)sBuf;
    #pragma unroll
    for (int i = 0; i < 32; i += 4) {
        float4 o4;
        o4.x = hr = c[i + 0] * hr + v[i + 0];
        o4.y = hr = c[i + 1] * hr + v[i + 1];
        o4.z = hr = c[i + 2] * hr + v[i + 2];
        o4.w = hr = c[i + 3] * hr + v[i + 3];
        *(float4*)&sO[t * 36 + i] = o4;
    }
    __syncthreads();                                           // barrier 3

    float4* op4 = (float4*)(out + ((size_t)b * H_ + k) * L_);
    #pragma unroll
    for (int j = 0; j < 8; ++j) {
        int idx = t + 256 * j;               // float4 index 0..2047
        int cc = idx >> 3, ss = idx & 7;     // chunk 32 floats, pad to 36
        op4[idx] = *(const float4*)&sO[cc * 36 + ss * 4];
    }
}

// ---------------- fallback: fully fused naive (if ws too small) -------------
__global__ __launch_bounds__(256) void fused_naive(const float* __restrict__ x,
                                                   const float* __restrict__ W,
                                                   const float* __restrict__ bias,
                                                   float* __restrict__ out) {
    __shared__ float Wh[512];
    __shared__ float Wg[512];
    __shared__ float sA[256];
    __shared__ float sB[256];
    const int bid = blockIdx.x;
    const int b = bid >> 9;
    const int k = bid & 511;
    const int t = threadIdx.x;

    for (int i = t; i < 512; i += 256) {
        Wh[i] = W[(size_t)k * D_ + i];
        Wg[i] = W[(size_t)(H_ + k) * D_ + i];
    }
    const float bh = bias[k];
    const float bg = bias[H_ + k];
    __syncthreads();

    float Hc = 0.f;
    const float* xb = x + (size_t)b * D_ * L_;
    for (int ch = 0; ch < 32; ++ch) {
        const int l = ch * 256 + t;
        float ah = bh, ag = bg;
        for (int d = 0; d < 512; ++d) {
            float xv = xb[(size_t)d * L_ + l];
            ah += Wh[d] * xv;
            ag += Wg[d] * xv;
        }
        float e   = __expf(ag);
        float inv = 1.f / (1.f + e);
        float ci  = inv;
        float zi  = e * inv;
        float gv  = (ah >= 0.f) ? (1.f + ah) : __expf(ah);
        float vi  = zi * gv;

        float A = ci, Bv = vi;
        sA[t] = A; sB[t] = Bv;
        __syncthreads();
        for (int off = 1; off < 256; off <<= 1) {
            float pA = 1.f, pB = 0.f;
            if (t >= off) { pA = sA[t - off]; pB = sB[t - off]; }
            __syncthreads();
            Bv = Bv + A * pB;
            A  = A * pA;
            sA[t] = A; sB[t] = Bv;
            __syncthreads();
        }
        out[((size_t)b * H_ + k) * L_ + l] = A * Hc + Bv;
        float An = sA[255], Bn = sB[255];
        Hc = An * Hc + Bn;
        __syncthreads();
    }
}

extern "C" void kernel_launch(void* const* d_in, const int* in_sizes, int n_in,
                              void* d_out, int out_size, void* d_ws, size_t ws_size,
                              hipStream_t stream) {
    const float* x    = (const float*)d_in[0];
    const float* W    = (const float*)d_in[1];
    const float* bias = (const float*)d_in[2];
    float* out = (float*)d_out;

    const size_t Wr_bytes = (size_t)O2_ * D_ * 2;            //   1,048,576
    const size_t hg_bytes = (size_t)B_ * O2_ * L_ * 2;       // 134,217,728
    const size_t need = Wr_bytes + hg_bytes;                 // ~135 MB

    if (ws_size >= need) {
        char* ws = (char*)d_ws;
        unsigned short* Wr = (unsigned short*)ws;
        __half*         hg = (__half*)(ws + Wr_bytes);

        prep_w<<<512, 256, 0, stream>>>(W, Wr);
        gemm_fused<<<dim3(L_ / 128, O2_ / 128, B_), 256, 0, stream>>>(x, Wr, hg);
        scan_seq<<<B_ * H_, 256, 0, stream>>>(hg, bias, out);
    } else {
        fused_naive<<<B_ * H_, 256, 0, stream>>>(x, W, bias, out);
    }
}

// Round 9
// 339.729 us; speedup vs baseline: 1.1921x; 1.0659x over previous
//
#include <hip/hip_runtime.h>
#include <hip/hip_fp16.h>
#include <hip/hip_bf16.h>

#define B_  8
#define D_  512
#define H_  512
#define L_  8192
#define O2_ 1024   // 2*H

typedef __attribute__((ext_vector_type(8))) short   bf16x8;
typedef __attribute__((ext_vector_type(4))) float   floatx4;
typedef __attribute__((ext_vector_type(8))) unsigned short ushort8_t;
typedef __attribute__((ext_vector_type(4))) unsigned short ushort4_t;

__device__ __forceinline__ unsigned short f2bf(float f) {
    union { float f; unsigned u; } x; x.f = f;
    unsigned u = x.u;
    u += 0x7FFFu + ((u >> 16) & 1u);   // round-to-nearest-even
    return (unsigned short)(u >> 16);
}

// packed f32->bf16 RNE via the core hip_bf16.h conversion (ROCm 7.x);
// compiler lowers the pair+pack to v_cvt(_pk)_bf16_f32 — no inline asm.
__device__ __forceinline__ unsigned cvt_pk_bf16(float lo, float hi) {
    __hip_bfloat16 blo = __float2bfloat16(lo);
    __hip_bfloat16 bhi = __float2bfloat16(hi);
    unsigned short slo = *reinterpret_cast<const unsigned short*>(&blo);
    unsigned short shi = *reinterpret_cast<const unsigned short*>(&bhi);
    return (unsigned)slo | ((unsigned)shi << 16);
}

// async global->LDS, 16B per lane; LDS dest = wave-uniform base + lane*16
__device__ __forceinline__ void async_load16(const void* g, void* l) {
    __builtin_amdgcn_global_load_lds(
        (const __attribute__((address_space(1))) unsigned int*)g,
        (__attribute__((address_space(3))) unsigned int*)l,
        16, 0, 0);
}

// ---------------- K0: reorder W rows (pair-interleave) + convert to bf16 ----
__global__ __launch_bounds__(256) void prep_w(const float* __restrict__ W,
                                              unsigned short* __restrict__ Wr) {
    int idx  = blockIdx.x * 256 + threadIdx.x;
    int flat = idx * 4;
    int o = flat >> 9;        // /512
    int d = flat & 511;
    int src_o = (o & 1) ? (H_ + (o >> 1)) : (o >> 1);
    float4 wv = *(const float4*)(W + (size_t)src_o * D_ + d);
    ushort4_t r;
    r.x = f2bf(wv.x); r.y = f2bf(wv.y); r.z = f2bf(wv.z); r.w = f2bf(wv.w);
    *(ushort4_t*)(Wr + (size_t)o * D_ + d) = r;
}

// ---------------- K1: hg = Wr @ x  (transpose FUSED into B-staging) ---------
// 128x128 / 4-wave / 2-barrier structure.
// A: DMA from Wr, perm_A(r) = r&7 — conflict-free both sides (unchanged).
// B: reg-staged transpose of x [D][L] fp32 -> Bs bf16 with
//      perm_B(l) = (l&7) ^ ((l>>3)&3)   (same function write & read)
//    - write phase (l=4c+j, c=0..7): (4(c&1)+j) ^ ((c>>1)&3) -> 8 distinct ✓
//    - read phase (l=base16+lm, lm=0..7 / 8..15): (l&7) distinct, (l>>3)&3
//      constant -> 8 distinct ✓        (r4's perm was 2-way on reads)
//    cvt via __float2bfloat16 pairs (compiler packs; ~3 VALU / 2 elems).
// Grid (l,o,b): 8 o-siblings sharing an x l-panel land on one XCD (flat IDs
// spaced 64 = 0 mod 8) -> panel fetched once per L2 (FETCH 98MB confirmed).
__global__ __launch_bounds__(256) void gemm_fused(const float* __restrict__ x,
                                                  const unsigned short* __restrict__ Wr,
                                                  __half* __restrict__ hg) {
    __shared__ __align__(16) unsigned short As[128][64];   // 16 KB
    __shared__ __align__(16) unsigned short Bs[128][64];   // 16 KB

    const int b  = blockIdx.z;
    const int l0 = blockIdx.x * 128;     // l fastest -> o-siblings same XCD
    const int o0 = blockIdx.y * 128;
    const int tid  = threadIdx.x;
    const int lane = tid & 63;
    const int w    = tid >> 6;
    const int wm   = (w >> 1) * 64;
    const int wn   = (w & 1) * 64;
    const int lm   = lane & 15;
    const int quad = lane >> 4;

    // A staging: lane i -> row +(i>>3), phys chunk i&7 sources logical (i&7)^(i>>3)
    const int sj  = lane >> 3;
    const int scg = (lane & 7) ^ sj;
    const unsigned short* Ag = Wr + (size_t)(o0 + w * 32 + sj) * D_ + scg * 8;

    // B staging: thread owns rows d = g*8..g*8+7, cols l = c*4..c*4+3
    const int c = tid & 31;
    const int g = tid >> 5;
    const float* xg = x + ((size_t)b * D_ + g * 8) * L_ + l0 + c * 4;

    // hoisted B write slots (kk-invariant): phys = g ^ perm_B(l)
    unsigned short* bw[4];
    #pragma unroll
    for (int j = 0; j < 4; ++j) {
        const int l = c * 4 + j;
        bw[j] = &Bs[l][(g ^ (l & 7) ^ ((l >> 3) & 3)) * 8];
    }

    float4 xr[8];
    #pragma unroll
    for (int rr = 0; rr < 8; ++rr)
        xr[rr] = *(const float4*)(xg + (size_t)rr * L_);

    floatx4 acc[4][4];
    #pragma unroll
    for (int mi = 0; mi < 4; ++mi)
        #pragma unroll
        for (int ni = 0; ni < 4; ++ni)
            acc[mi][ni] = (floatx4){0.f, 0.f, 0.f, 0.f};

    // read-side perm_B pieces: perm_B(r) = (lm&7) ^ ((ni*2 + (lm>>3)) & 3)
    const int pbm = lm & 7;
    const int pbh = lm >> 3;

    for (int kk = 0; kk < 8; ++kk) {
        const int k0 = kk * 64;
        // A: DMA issue (4 x 1KB per wave)
        #pragma unroll
        for (int p = 0; p < 4; ++p)
            async_load16(Ag + (size_t)(p * 8) * D_ + k0, &As[w * 32 + p * 8][0]);

        // B: register transpose + packed cvt + swizzled 16B ds_writes
        #pragma unroll
        for (int j = 0; j < 4; ++j) {
            uint4 o4;
            o4.x = cvt_pk_bf16(((const float*)&xr[0])[j], ((const float*)&xr[1])[j]);
            o4.y = cvt_pk_bf16(((const float*)&xr[2])[j], ((const float*)&xr[3])[j]);
            o4.z = cvt_pk_bf16(((const float*)&xr[4])[j], ((const float*)&xr[5])[j]);
            o4.w = cvt_pk_bf16(((const float*)&xr[6])[j], ((const float*)&xr[7])[j]);
            *(uint4*)bw[j] = o4;
        }

        __syncthreads();   // drains A-DMA (vmcnt) + B ds_writes (lgkm)

        // prefetch next x-tile: flies under the MFMA phase
        if (kk < 7) {
            #pragma unroll
            for (int rr = 0; rr < 8; ++rr)
                xr[rr] = *(const float4*)(xg + (size_t)((kk + 1) * 64 + rr) * L_);
        }

        #pragma unroll
        for (int ks = 0; ks < 2; ++ks) {
            const int lc = ks * 4 + quad;      // logical 16B chunk (=koff/8)
            bf16x8 af[4], bfv[4];
            #pragma unroll
            for (int mi = 0; mi < 4; ++mi) {
                const int r = wm + mi * 16 + lm;
                af[mi] = *(const bf16x8*)&As[r][(lc ^ (r & 7)) * 8];
            }
            #pragma unroll
            for (int ni = 0; ni < 4; ++ni) {
                const int r = wn + ni * 16 + lm;
                const int permB = pbm ^ ((ni * 2 + pbh) & 3);
                bfv[ni] = *(const bf16x8*)&Bs[r][(lc ^ permB) * 8];
            }
            #pragma unroll
            for (int mi = 0; mi < 4; ++mi)
                #pragma unroll
                for (int ni = 0; ni < 4; ++ni)
                    acc[mi][ni] = __builtin_amdgcn_mfma_f32_16x16x32_bf16(
                        af[mi], bfv[ni], acc[mi][ni], 0, 0, 0);
        }

        // trailing sync: lgkm-only so the x-prefetch stays in flight (T14)
        asm volatile("s_waitcnt lgkmcnt(0)" ::: "memory");
        __builtin_amdgcn_s_barrier();
        asm volatile("" ::: "memory");
    }

    // epilogue: D[row=quad*4+r][col=lm] per 16x16 tile (proven mapping)
    __half* hp = hg + ((size_t)b * O2_ + o0 + wm + quad * 4) * L_ + l0 + wn + lm;
    for (int mi = 0; mi < 4; ++mi)
        for (int ni = 0; ni < 4; ++ni)
            for (int r = 0; r < 4; ++r)
                hp[(size_t)(mi * 16 + r) * L_ + ni * 16] = __float2half(acc[mi][ni][r]);
}

// ---------------- K2: per-(b,k) chunked scan — shfl wave scan, 3 barriers ---
__global__ __launch_bounds__(256) void scan_seq(const __half* __restrict__ hg,
                                                const float* __restrict__ bias,
                                                float* __restrict__ out) {
    __shared__ __align__(16) unsigned int sBuf[256 * 40];
    __shared__ float wA[4];
    __shared__ float wB[4];
    unsigned int* sH = sBuf;
    unsigned int* sG = sBuf + 256 * 20;

    const int bid = blockIdx.x;
    const int b = bid >> 9;
    const int k = bid & 511;
    const int t = threadIdx.x;
    const int lane = t & 63;
    const int wid  = t >> 6;

    const uint4* hq = (const uint4*)(hg + ((size_t)b * O2_ + 2 * k) * L_);
    const uint4* gq = hq + (L_ / 8);   // next row (gate)

    #pragma unroll
    for (int j = 0; j < 4; ++j) {
        int idx = t + 256 * j;               // uint4 index 0..1023
        uint4 hv = hq[idx];
        uint4 gv = gq[idx];
        int cc = idx >> 2, ss = idx & 3;     // chunk 16 uints, pad to 20
        *(uint4*)&sH[cc * 20 + ss * 4] = hv;
        *(uint4*)&sG[cc * 20 + ss * 4] = gv;
    }
    const float bh = bias[k];
    const float bg = bias[H_ + k];
    __syncthreads();                                           // barrier 1

    float c[32], v[32];
    float A = 1.f, Bv = 0.f;
    #pragma unroll
    for (int j4 = 0; j4 < 4; ++j4) {
        uint4 hv = *(const uint4*)&sH[t * 20 + j4 * 4];
        uint4 gv = *(const uint4*)&sG[t * 20 + j4 * 4];
        unsigned hu[4] = {hv.x, hv.y, hv.z, hv.w};
        unsigned gu[4] = {gv.x, gv.y, gv.z, gv.w};
        #pragma unroll
        for (int q = 0; q < 4; ++q) {
            __half2 h2 = *(const __half2*)&hu[q];
            __half2 g2 = *(const __half2*)&gu[q];
            #pragma unroll
            for (int e = 0; e < 2; ++e) {
                const int i = j4 * 8 + q * 2 + e;
                float hf = (e ? __high2float(h2) : __low2float(h2)) + bh;
                float gf = (e ? __high2float(g2) : __low2float(g2)) + bg;
                float ex  = __expf(gf);
                float inv = 1.f / (1.f + ex);
                float ci  = inv;        // sigmoid(-gate)
                float zi  = ex * inv;   // sigmoid(gate)
                float gv2 = (hf >= 0.f) ? (1.f + hf) : __expf(hf);
                float vi  = zi * gv2;
                c[i] = ci; v[i] = vi;
                Bv = ci * Bv + vi;
                A *= ci;
            }
        }
    }

    // wave-level inclusive scan of (A,B) composition, no barriers
    #pragma unroll
    for (int off = 1; off < 64; off <<= 1) {
        float pA = __shfl_up(A, off);
        float pB = __shfl_up(Bv, off);
        if (lane >= off) { Bv = Bv + A * pB; A = A * pA; }
    }

    if (lane == 63) { wA[wid] = A; wB[wid] = Bv; }
    __syncthreads();                                           // barrier 2

    // carry from preceding waves (composed in order)
    float cB = 0.f;
    for (int p = 0; p < wid; ++p) cB = wB[p] + wA[p] * cB;

    // exclusive lane prefix within wave
    float eA = __shfl_up(A, 1);
    float eB = __shfl_up(Bv, 1);
    if (lane == 0) { eA = 1.f; eB = 0.f; }
    float hr = eB + eA * cB;   // H entering this thread's chunk (H0 = 0)

    // outputs into LDS (chunk stride 36 floats), then coalesced store.
    float* sO = (float*)sBuf;
    #pragma unroll
    for (int i = 0; i < 32; i += 4) {
        float4 o4;
        o4.x = hr = c[i + 0] * hr + v[i + 0];
        o4.y = hr = c[i + 1] * hr + v[i + 1];
        o4.z = hr = c[i + 2] * hr + v[i + 2];
        o4.w = hr = c[i + 3] * hr + v[i + 3];
        *(float4*)&sO[t * 36 + i] = o4;
    }
    __syncthreads();                                           // barrier 3

    float4* op4 = (float4*)(out + ((size_t)b * H_ + k) * L_);
    #pragma unroll
    for (int j = 0; j < 8; ++j) {
        int idx = t + 256 * j;               // float4 index 0..2047
        int cc = idx >> 3, ss = idx & 7;     // chunk 32 floats, pad to 36
        op4[idx] = *(const float4*)&sO[cc * 36 + ss * 4];
    }
}

// ---------------- fallback: fully fused naive (if ws too small) -------------
__global__ __launch_bounds__(256) void fused_naive(const float* __restrict__ x,
                                                   const float* __restrict__ W,
                                                   const float* __restrict__ bias,
                                                   float* __restrict__ out) {
    __shared__ float Wh[512];
    __shared__ float Wg[512];
    __shared__ float sA[256];
    __shared__ float sB[256];
    const int bid = blockIdx.x;
    const int b = bid >> 9;
    const int k = bid & 511;
    const int t = threadIdx.x;

    for (int i = t; i < 512; i += 256) {
        Wh[i] = W[(size_t)k * D_ + i];
        Wg[i] = W[(size_t)(H_ + k) * D_ + i];
    }
    const float bh = bias[k];
    const float bg = bias[H_ + k];
    __syncthreads();

    float Hc = 0.f;
    const float* xb = x + (size_t)b * D_ * L_;
    for (int ch = 0; ch < 32; ++ch) {
        const int l = ch * 256 + t;
        float ah = bh, ag = bg;
        for (int d = 0; d < 512; ++d) {
            float xv = xb[(size_t)d * L_ + l];
            ah += Wh[d] * xv;
            ag += Wg[d] * xv;
        }
        float e   = __expf(ag);
        float inv = 1.f / (1.f + e);
        float ci  = inv;
        float zi  = e * inv;
        float gv  = (ah >= 0.f) ? (1.f + ah) : __expf(ah);
        float vi  = zi * gv;

        float A = ci, Bv = vi;
        sA[t] = A; sB[t] = Bv;
        __syncthreads();
        for (int off = 1; off < 256; off <<= 1) {
            float pA = 1.f, pB = 0.f;
            if (t >= off) { pA = sA[t - off]; pB = sB[t - off]; }
            __syncthreads();
            Bv = Bv + A * pB;
            A  = A * pA;
            sA[t] = A; sB[t] = Bv;
            __syncthreads();
        }
        out[((size_t)b * H_ + k) * L_ + l] = A * Hc + Bv;
        float An = sA[255], Bn = sB[255];
        Hc = An * Hc + Bn;
        __syncthreads();
    }
}

extern "C" void kernel_launch(void* const* d_in, const int* in_sizes, int n_in,
                              void* d_out, int out_size, void* d_ws, size_t ws_size,
                              hipStream_t stream) {
    const float* x    = (const float*)d_in[0];
    const float* W    = (const float*)d_in[1];
    const float* bias = (const float*)d_in[2];
    float* out = (float*)d_out;

    const size_t Wr_bytes = (size_t)O2_ * D_ * 2;            //   1,048,576
    const size_t hg_bytes = (size_t)B_ * O2_ * L_ * 2;       // 134,217,728
    const size_t need = Wr_bytes + hg_bytes;                 // ~135 MB

    if (ws_size >= need) {
        char* ws = (char*)d_ws;
        unsigned short* Wr = (unsigned short*)ws;
        __half*         hg = (__half*)(ws + Wr_bytes);

        prep_w<<<512, 256, 0, stream>>>(W, Wr);
        gemm_fused<<<dim3(L_ / 128, O2_ / 128, B_), 256, 0, stream>>>(x, Wr, hg);
        scan_seq<<<B_ * H_, 256, 0, stream>>>(hg, bias, out);
    } else {
        fused_naive<<<B_ * H_, 256, 0, stream>>>(x, W, bias, out);
    }
}